// Round 15
// baseline (126.385 us; speedup 1.0000x reference)
//
#include <hip/hip_runtime.h>
#include <hip/hip_bf16.h>

#define B_   2
#define S_   2048
#define D_   768
#define H_   12
#define DK_  64
#define R_   (B_*S_)   // 4096 rows total
#define LOG2E_OVER8 0.18033688011112042f

typedef __attribute__((ext_vector_type(8))) short short8;
typedef __attribute__((ext_vector_type(4))) float f32x4;

__device__ __forceinline__ short f2b(float f) {
  union { float f; unsigned u; } x; x.f = f;
  unsigned r = x.u + 0x7fffu + ((x.u >> 16) & 1u);
  return (short)(r >> 16);
}

__device__ __forceinline__ unsigned cvt_pk_bf16(float lo, float hi) {
  unsigned r;
  asm("v_cvt_pk_bf16_f32 %0, %1, %2" : "=v"(r) : "v"(lo), "v"(hi));
  return r;
}

__device__ __forceinline__ void gl_lds16(const short* g, short* l) {
  __builtin_amdgcn_global_load_lds(
      (const __attribute__((address_space(1))) void*)g,
      (__attribute__((address_space(3))) void*)l, 16, 0, 0);
}

// ---------------- fp32 -> bf16 conversion (x + 4 weights) ----------------
__global__ void cvt_kernel(const float* __restrict__ x,
                           const float* __restrict__ wq, const float* __restrict__ wk,
                           const float* __restrict__ wv, const float* __restrict__ wo,
                           short* __restrict__ xb, short* __restrict__ wb) {
  const int XQ = R_ * D_ / 4;
  const int WQ = D_ * D_ / 4;
  int idx = blockIdx.x * blockDim.x + threadIdx.x;
  const float* src; short* dst; int off;
  if (idx < XQ) { src = x; dst = xb; off = idx; }
  else {
    int wi = idx - XQ; int w = wi / WQ; off = wi - w * WQ;
    if      (w == 0) { src = wq; dst = wb; }
    else if (w == 1) { src = wk; dst = wb + D_*D_; }
    else if (w == 2) { src = wv; dst = wb + 2*D_*D_; }
    else             { src = wo; dst = wb + 3*D_*D_; }
  }
  float4 v = ((const float4*)src)[off];
  short4 o;
  o.x = f2b(v.x); o.y = f2b(v.y); o.z = f2b(v.z); o.w = f2b(v.w);
  ((short4*)dst)[off] = o;
}

// ---------------- QKV projection (128x128, BK=32, dbuf — round-10 proven) ----------
__launch_bounds__(256)
__global__ void qkv_gemm_kernel(const short* __restrict__ xb, const short* __restrict__ wb,
                                const float* __restrict__ bq, const float* __restrict__ bk,
                                const float* __restrict__ bv,
                                short* __restrict__ Qw, short* __restrict__ Kw,
                                short* __restrict__ VTw) {
  __shared__ short As[2][128 * 32];
  __shared__ short Bs[2][128 * 32];
  const int which = blockIdx.z;
  const short* W = wb + which * (D_ * D_);
  const float* bias = (which == 0) ? bq : (which == 1) ? bk : bv;
  const int n0 = blockIdx.x * 128, m0 = blockIdx.y * 128;
  const int t = threadIdx.x, l = t & 63, w = t >> 6;
  const int wr = w >> 1, wc = w & 1;

  f32x4 acc[4][4] = {};
  const int srow = t >> 2, sseg = (t & 3) * 8;

#define GSTAGE(buf, k0) do { \
    gl_lds16(xb + (m0 + srow) * D_ + (k0) + sseg,      &As[buf][t * 8]); \
    gl_lds16(xb + (m0 + 64 + srow) * D_ + (k0) + sseg, &As[buf][(t + 256) * 8]); \
    gl_lds16(W  + (n0 + srow) * D_ + (k0) + sseg,      &Bs[buf][t * 8]); \
    gl_lds16(W  + (n0 + 64 + srow) * D_ + (k0) + sseg, &Bs[buf][(t + 256) * 8]); \
  } while (0)

  GSTAGE(0, 0);
  __syncthreads();
  int cur = 0;
  for (int k0 = 0; k0 < D_; k0 += 32) {
    if (k0 + 32 < D_) GSTAGE(cur ^ 1, k0 + 32);
    short8 a[4], b[4];
#pragma unroll
    for (int i = 0; i < 4; i++)
      a[i] = *(const short8*)&As[cur][(wr * 64 + i * 16 + (l & 15)) * 32 + (l >> 4) * 8];
#pragma unroll
    for (int i = 0; i < 4; i++)
      b[i] = *(const short8*)&Bs[cur][(wc * 64 + i * 16 + (l & 15)) * 32 + (l >> 4) * 8];
#pragma unroll
    for (int i = 0; i < 4; i++)
#pragma unroll
      for (int j = 0; j < 4; j++)
        acc[i][j] = __builtin_amdgcn_mfma_f32_16x16x32_bf16(a[i], b[j], acc[i][j], 0, 0, 0);
    __syncthreads();
    cur ^= 1;
  }
#undef GSTAGE

#pragma unroll
  for (int i = 0; i < 4; i++) {
#pragma unroll
    for (int j2 = 0; j2 < 4; j2++) {
      int mm = m0 + wr * 64 + i * 16 + (l >> 4) * 4 + j2;
      int bidx = mm >> 11, s = mm & 2047;
#pragma unroll
      for (int nj = 0; nj < 4; nj++) {
        int e = n0 + wc * 64 + nj * 16 + (l & 15);
        float val = acc[i][nj][j2] + bias[e];
        int h = e >> 6, dk = e & 63;
        int bh = bidx * H_ + h;
        if (which == 0)      Qw[(bh * S_ + s) * DK_ + dk] = f2b(val * LOG2E_OVER8);
        else if (which == 1) Kw[(bh * S_ + s) * DK_ + dk] = f2b(val);
        else                 VTw[(bh * DK_ + dk) * S_ + s] = f2b(val);
      }
    }
  }
}

// -------- flash attention v12: wave-private staging, ZERO in-loop barriers --------
// 128 threads = 2 waves. Wave w owns kv half [w*1024,(w+1)*1024) for the block's
// 32 q-rows. K/V LDS regions are WAVE-PRIVATE (race-free by construction); the
// only in-loop sync is per-wave counted s_waitcnt vmcnt(8):
//   each iter issues exactly 8 gl_lds16 (prefetch buf^1); vmcnt(8) retires the
//   PREVIOUS iter's 8 (which filled buf about to be read). WAR on buf^1 is safe:
//   its ds_reads retired (lgkmcnt before MFMA use) before this iter's issue.
// Per-tile math = v10 verbatim (fixed-scale exp2 softmax, in-reg P, remapped-k PV).
// One 2-way merge with the block's only two barriers at the end.
#define KVB   32
#define SHALF 1024
__launch_bounds__(128)
__global__ void attn_kernel(const short* __restrict__ Qw, const short* __restrict__ Kw,
                            const short* __restrict__ VTw, short* __restrict__ ctx) {
  __shared__ short Ksh[2][2][KVB * DK_];   // [wave][buf][32 kv rows][64] = 16KB
  __shared__ short Vsh[2][2][KVB * DK_];   // [wave][buf] pair-packed      = 16KB

  const int t = threadIdx.x, l = t & 63, w = t >> 6;
  // bijective XCD swizzle: 1536 blocks -> (xcd, head-in-xcd, q-block of 32)
  const int L = blockIdx.y * 64 + blockIdx.x;
  const int xcd = L & 7, idx = L >> 3;          // idx in [0,192)
  const int bh = xcd * 3 + (idx >> 6);
  const int q0 = (idx & 63) * 32;
  const int bq = bh / H_, h = bh - bq * H_;
  const short* Qh = Qw + bh * S_ * DK_;
  const short* Kh = Kw + (bh * S_ + w * SHALF) * DK_;
  const short* Vh = VTw + bh * DK_ * S_ + w * SHALF;

  // per-lane staging: chunk i = l + 64j (j<4). K: row r=(l>>3)+8j, c=l&7,
  // src col-chunk = c ^ (r&7) = c0^r0 (j-invariant since r&7 == r0 < 8).
  const int r0 = l >> 3, c0 = l & 7;
  const int koff0 = r0 * DK_ + ((c0 ^ r0) << 3);
  const int vc8 = c0 ^ r0;                      // j-invariant
  const int vr0 = 2 * r0 + (vc8 >> 2);
  const int voff0 = vr0 * S_ + ((vc8 & 3) << 3);

#define STAGE(buf, kt) do { \
    _Pragma("unroll") \
    for (int j = 0; j < 4; j++) \
      gl_lds16(Kh + (kt) * DK_ + koff0 + 8 * j * DK_, &Ksh[w][buf][(l + 64 * j) * 8]); \
    _Pragma("unroll") \
    for (int j = 0; j < 4; j++) \
      gl_lds16(Vh + (kt) + voff0 + 16 * S_ * j,       &Vsh[w][buf][(l + 64 * j) * 8]); \
  } while (0)

  // Q fragments in registers (pre-scaled by log2e/8 at projection)
  short8 qf[2][2];
#pragma unroll
  for (int mi = 0; mi < 2; mi++)
#pragma unroll
    for (int ks = 0; ks < 2; ks++)
      qf[mi][ks] = *(const short8*)&Qh[(q0 + 16 * mi + (l & 15)) * DK_ + ks * 32 + (l >> 4) * 8];

  f32x4 acc_o[2][4] = {};
  float l_run[2] = {0.f, 0.f};

  STAGE(0, 0);
  int cur = 0;

  for (int kt = 0; kt < SHALF; kt += KVB) {
    if (kt + KVB < SHALF) {
      STAGE(cur ^ 1, kt + KVB);                           // 8 loads in flight
      asm volatile("s_waitcnt vmcnt(8)" ::: "memory");    // prev iter's 8 (-> buf cur) done
    } else {
      asm volatile("s_waitcnt vmcnt(0)" ::: "memory");    // final tile drain
    }
    __builtin_amdgcn_sched_barrier(0);

    // ---- QK^T (swapped): lane holds scores for q=l&15(+16mi), k=16ni+4(l>>4)+j ----
    f32x4 acc_s[2][2] = {};
    __builtin_amdgcn_s_setprio(1);
#pragma unroll
    for (int ni = 0; ni < 2; ni++) {
      int r = (l & 15) + 16 * ni;
#pragma unroll
      for (int ks = 0; ks < 2; ks++) {
        int cc = (l >> 4) + 4 * ks;
        short8 kf = *(const short8*)&Ksh[w][cur][r * DK_ + ((cc ^ (r & 7)) << 3)];
        acc_s[0][ni] = __builtin_amdgcn_mfma_f32_16x16x32_bf16(kf, qf[0][ks], acc_s[0][ni], 0, 0, 0);
        acc_s[1][ni] = __builtin_amdgcn_mfma_f32_16x16x32_bf16(kf, qf[1][ks], acc_s[1][ni], 0, 0, 0);
      }
    }
    __builtin_amdgcn_s_setprio(0);

    // ---- fixed-scale softmax: p = exp2(score), per-lane partial sums ----
#pragma unroll
    for (int mi = 0; mi < 2; mi++) {
      float sum = 0.f;
#pragma unroll
      for (int ni = 0; ni < 2; ni++)
#pragma unroll
        for (int j = 0; j < 4; j++) {
          float p = __builtin_amdgcn_exp2f(acc_s[mi][ni][j]);
          acc_s[mi][ni][j] = p;
          sum += p;
        }
      l_run[mi] += sum;
    }

    // ---- pack P in-register (k-order: lane-group c owns {4c+j, 16+4c+j}) ----
    union PK { unsigned u[4]; short8 v; } pa0, pa1;
    pa0.u[0] = cvt_pk_bf16(acc_s[0][0][0], acc_s[0][0][1]);
    pa0.u[1] = cvt_pk_bf16(acc_s[0][0][2], acc_s[0][0][3]);
    pa0.u[2] = cvt_pk_bf16(acc_s[0][1][0], acc_s[0][1][1]);
    pa0.u[3] = cvt_pk_bf16(acc_s[0][1][2], acc_s[0][1][3]);
    pa1.u[0] = cvt_pk_bf16(acc_s[1][0][0], acc_s[1][0][1]);
    pa1.u[1] = cvt_pk_bf16(acc_s[1][0][2], acc_s[1][0][3]);
    pa1.u[2] = cvt_pk_bf16(acc_s[1][1][0], acc_s[1][1][1]);
    pa1.u[3] = cvt_pk_bf16(acc_s[1][1][2], acc_s[1][1][3]);

    // ---- PV: B = V rows in the SAME remapped k-order, read b64x2 from LDS ----
    __builtin_amdgcn_s_setprio(1);
    {
      const int cc = l >> 4;
      union V8 { short4 h[2]; short8 v; };
#pragma unroll
      for (int nd = 0; nd < 4; nd++) {
        int vr = (l & 15) + 16 * nd, rp = vr >> 1;
        int ph0 = (((vr & 1) << 2) | (cc >> 1)) ^ (rp & 7);
        int ph1 = (((vr & 1) << 2) | (2 + (cc >> 1))) ^ (rp & 7);
        V8 vf;
        vf.h[0] = *(const short4*)&Vsh[w][cur][rp * 64 + ph0 * 8 + (cc & 1) * 4];
        vf.h[1] = *(const short4*)&Vsh[w][cur][rp * 64 + ph1 * 8 + (cc & 1) * 4];
        acc_o[0][nd] = __builtin_amdgcn_mfma_f32_16x16x32_bf16(pa0.v, vf.v, acc_o[0][nd], 0, 0, 0);
        acc_o[1][nd] = __builtin_amdgcn_mfma_f32_16x16x32_bf16(pa1.v, vf.v, acc_o[1][nd], 0, 0, 0);
      }
    }
    __builtin_amdgcn_s_setprio(0);

    cur ^= 1;   // NO barrier: Ksh[w]/Vsh[w] are wave-private
  }

  // ---- reduce per-lane l partials across the 4 lane-groups (once) ----
#pragma unroll
  for (int mi = 0; mi < 2; mi++) {
    l_run[mi] += __shfl_xor(l_run[mi], 16);
    l_run[mi] += __shfl_xor(l_run[mi], 32);
  }

  // ---- 2-way merge: wave 1 publishes, wave 0 combines & writes ----
  __syncthreads();                          // K/V LDS dead from here (only block barrier #1)
  float* Oshf = (float*)&Ksh[0][0][0];      // 32 q x 64 d = 2048 floats (8KB, fits 16KB)
  float* Lsh  = (float*)&Vsh[0][0][0];      // l partials: [mi][16]
  if (w == 1) {
#pragma unroll
    for (int mi = 0; mi < 2; mi++)
#pragma unroll
      for (int nd = 0; nd < 4; nd++)
#pragma unroll
        for (int j = 0; j < 4; j++)
          Oshf[(16 * mi + (l >> 4) * 4 + j) * 64 + (l & 15) + 16 * nd] = acc_o[mi][nd][j];
    if (l < 16) {
      Lsh[l]      = l_run[0];
      Lsh[16 + l] = l_run[1];
    }
  }
  __syncthreads();                          // block barrier #2
  if (w == 0) {
#pragma unroll
    for (int mi = 0; mi < 2; mi++) {
#pragma unroll
      for (int j = 0; j < 4; j++) {
        int src = ((l >> 4) << 2) + j;      // q-row within 16, also the source lane
        float llo = __shfl(l_run[mi], src);
        float lhi = Lsh[mi * 16 + src];
        float inv = 1.f / (llo + lhi);
        int srow = q0 + 16 * mi + src;
#pragma unroll
        for (int nd = 0; nd < 4; nd++) {
          float ohi = Oshf[(16 * mi + src) * 64 + (l & 15) + 16 * nd];
          float val = (acc_o[mi][nd][j] + ohi) * inv;
          ctx[(bq * S_ + srow) * D_ + h * DK_ + (l & 15) + 16 * nd] = f2b(val);
        }
      }
    }
  }
#undef STAGE
}

// ---------------- output projection (128x128, BK=32, dbuf — round-10 proven) -------
__launch_bounds__(256)
__global__ void oproj_kernel(const short* __restrict__ ctx, const short* __restrict__ Wo,
                             const float* __restrict__ bo, float* __restrict__ out) {
  __shared__ short As[2][128 * 32];
  __shared__ short Bs[2][128 * 32];
  const int n0 = blockIdx.x * 128, m0 = blockIdx.y * 128;
  const int t = threadIdx.x, l = t & 63, w = t >> 6;
  const int wr = w >> 1, wc = w & 1;

  f32x4 acc[4][4] = {};
  const int srow = t >> 2, sseg = (t & 3) * 8;

#define GSTAGE(buf, k0) do { \
    gl_lds16(ctx + (m0 + srow) * D_ + (k0) + sseg,      &As[buf][t * 8]); \
    gl_lds16(ctx + (m0 + 64 + srow) * D_ + (k0) + sseg, &As[buf][(t + 256) * 8]); \
    gl_lds16(Wo  + (n0 + srow) * D_ + (k0) + sseg,      &Bs[buf][t * 8]); \
    gl_lds16(Wo  + (n0 + 64 + srow) * D_ + (k0) + sseg, &Bs[buf][(t + 256) * 8]); \
  } while (0)

  GSTAGE(0, 0);
  __syncthreads();
  int cur = 0;
  for (int k0 = 0; k0 < D_; k0 += 32) {
    if (k0 + 32 < D_) GSTAGE(cur ^ 1, k0 + 32);
    short8 a[4], b[4];
#pragma unroll
    for (int i = 0; i < 4; i++)
      a[i] = *(const short8*)&As[cur][(wr * 64 + i * 16 + (l & 15)) * 32 + (l >> 4) * 8];
#pragma unroll
    for (int i = 0; i < 4; i++)
      b[i] = *(const short8*)&Bs[cur][(wc * 64 + i * 16 + (l & 15)) * 32 + (l >> 4) * 8];
#pragma unroll
    for (int i = 0; i < 4; i++)
#pragma unroll
      for (int j = 0; j < 4; j++)
        acc[i][j] = __builtin_amdgcn_mfma_f32_16x16x32_bf16(a[i], b[j], acc[i][j], 0, 0, 0);
    __syncthreads();
    cur ^= 1;
  }
#undef GSTAGE

#pragma unroll
  for (int i = 0; i < 4; i++) {
#pragma unroll
    for (int j2 = 0; j2 < 4; j2++) {
      int mm = m0 + wr * 64 + i * 16 + (l >> 4) * 4 + j2;
#pragma unroll
      for (int nj = 0; nj < 4; nj++) {
        int e = n0 + wc * 64 + nj * 16 + (l & 15);
        out[mm * D_ + e] = acc[i][nj][j2] + bo[e];
      }
    }
  }
}

extern "C" void kernel_launch(void* const* d_in, const int* in_sizes, int n_in,
                              void* d_out, int out_size, void* d_ws, size_t ws_size,
                              hipStream_t stream) {
  (void)in_sizes; (void)n_in; (void)out_size; (void)ws_size;
  const float* x  = (const float*)d_in[0];
  const float* wq = (const float*)d_in[1];
  const float* bq = (const float*)d_in[2];
  const float* wk = (const float*)d_in[3];
  const float* bk = (const float*)d_in[4];
  const float* wv = (const float*)d_in[5];
  const float* bv = (const float*)d_in[6];
  const float* wo = (const float*)d_in[7];
  const float* bo = (const float*)d_in[8];
  float* out = (float*)d_out;

  short* xb  = (short*)d_ws;            // R*D bf16
  short* wb  = xb + R_ * D_;            // 4*D*D bf16 (q,k,v,o)
  short* Qw  = wb + 4 * D_ * D_;        // [B,H,S,DK]
  short* Kw  = Qw + R_ * D_;            // [B,H,S,DK]
  short* VTw = Kw + R_ * D_;            // [B,H,DK,S]
  short* ctx = VTw + R_ * D_;           // [B,S,D]

  cvt_kernel<<<5376, 256, 0, stream>>>(x, wq, wk, wv, wo, xb, wb);
  qkv_gemm_kernel<<<dim3(6, 32, 3), 256, 0, stream>>>(xb, wb, bq, bk, bv, Qw, Kw, VTw);
  attn_kernel<<<dim3(64, 24), 128, 0, stream>>>(Qw, Kw, VTw, ctx);
  oproj_kernel<<<dim3(6, 32), 256, 0, stream>>>(ctx, wb + 3 * D_ * D_, bo, out);
}

// Round 16
// 100.582 us; speedup vs baseline: 1.2565x; 1.2565x over previous
//
#include <hip/hip_runtime.h>
#include <hip/hip_bf16.h>

#define B_   2
#define S_   2048
#define D_   768
#define H_   12
#define DK_  64
#define R_   (B_*S_)   // 4096 rows total
#define LOG2E_OVER8 0.18033688011112042f

typedef __attribute__((ext_vector_type(8))) short short8;
typedef __attribute__((ext_vector_type(4))) float f32x4;

__device__ __forceinline__ short f2b(float f) {
  union { float f; unsigned u; } x; x.f = f;
  unsigned r = x.u + 0x7fffu + ((x.u >> 16) & 1u);
  return (short)(r >> 16);
}

__device__ __forceinline__ unsigned cvt_pk_bf16(float lo, float hi) {
  unsigned r;
  asm("v_cvt_pk_bf16_f32 %0, %1, %2" : "=v"(r) : "v"(lo), "v"(hi));
  return r;
}

__device__ __forceinline__ void gl_lds16(const short* g, short* l) {
  __builtin_amdgcn_global_load_lds(
      (const __attribute__((address_space(1))) void*)g,
      (__attribute__((address_space(3))) void*)l, 16, 0, 0);
}

// ---------------- fp32 -> bf16 conversion (x + 4 weights) ----------------
// x-part blocks (0..3071) are XCD-remapped so xb rows [c*512,(c+1)*512) are
// written by XCD c — matching qkv's read mapping (L2 producer/consumer locality).
__global__ void cvt_kernel(const float* __restrict__ x,
                           const float* __restrict__ wq, const float* __restrict__ wk,
                           const float* __restrict__ wv, const float* __restrict__ wo,
                           short* __restrict__ xb, short* __restrict__ wb) {
  const int WQ = D_ * D_ / 4;   // float4 count per weight
  const int b = blockIdx.x;
  const float* src; short* dst; int off;
  if (b < 3072) {               // x part: XQ = 786432 float4 = 3072 blocks exactly
    int c = b & 7, j = b >> 3;  // 8 XCDs x 384 blocks (bijective)
    off = c * 98304 + j * 256 + threadIdx.x;   // 98304 = 512 rows * 192 f4/row
    src = x; dst = xb;
  } else {
    int wi = (b - 3072) * 256 + threadIdx.x;
    int w = wi / WQ; off = wi - w * WQ;
    if      (w == 0) { src = wq; dst = wb; }
    else if (w == 1) { src = wk; dst = wb + D_*D_; }
    else if (w == 2) { src = wv; dst = wb + 2*D_*D_; }
    else             { src = wo; dst = wb + 3*D_*D_; }
  }
  float4 v = ((const float4*)src)[off];
  short4 o;
  o.x = f2b(v.x); o.y = f2b(v.y); o.z = f2b(v.z); o.w = f2b(v.w);
  ((short4*)dst)[off] = o;
}

// ---------------- QKV projection (128x128, BK=32, dbuf — round-10 proven) ----------
// XCD swizzle: xcd owns xb rows [xcd*512, xcd*512+512) across all (which, n0):
// per-XCD L2 set = 0.77MB xb + 3.4MB W. 576 = 8 x 72 (bijective).
__launch_bounds__(256)
__global__ void qkv_gemm_kernel(const short* __restrict__ xb, const short* __restrict__ wb,
                                const float* __restrict__ bq, const float* __restrict__ bk,
                                const float* __restrict__ bv,
                                short* __restrict__ Qw, short* __restrict__ Kw,
                                short* __restrict__ VTw) {
  __shared__ short As[2][128 * 32];
  __shared__ short Bs[2][128 * 32];
  const int lid = (blockIdx.z * 32 + blockIdx.y) * 6 + blockIdx.x;
  const int xcd = lid & 7, ii = lid >> 3;        // ii in [0,72)
  const int rem = ii % 18;
  const int which = rem / 6;
  const int n0 = (rem % 6) * 128;
  const int m0 = (xcd * 4 + ii / 18) * 128;
  const short* W = wb + which * (D_ * D_);
  const float* bias = (which == 0) ? bq : (which == 1) ? bk : bv;
  const int t = threadIdx.x, l = t & 63, w = t >> 6;
  const int wr = w >> 1, wc = w & 1;

  f32x4 acc[4][4] = {};
  const int srow = t >> 2, sseg = (t & 3) * 8;

#define GSTAGE(buf, k0) do { \
    gl_lds16(xb + (m0 + srow) * D_ + (k0) + sseg,      &As[buf][t * 8]); \
    gl_lds16(xb + (m0 + 64 + srow) * D_ + (k0) + sseg, &As[buf][(t + 256) * 8]); \
    gl_lds16(W  + (n0 + srow) * D_ + (k0) + sseg,      &Bs[buf][t * 8]); \
    gl_lds16(W  + (n0 + 64 + srow) * D_ + (k0) + sseg, &Bs[buf][(t + 256) * 8]); \
  } while (0)

  GSTAGE(0, 0);
  __syncthreads();
  int cur = 0;
  for (int k0 = 0; k0 < D_; k0 += 32) {
    if (k0 + 32 < D_) GSTAGE(cur ^ 1, k0 + 32);
    short8 a[4], b[4];
#pragma unroll
    for (int i = 0; i < 4; i++)
      a[i] = *(const short8*)&As[cur][(wr * 64 + i * 16 + (l & 15)) * 32 + (l >> 4) * 8];
#pragma unroll
    for (int i = 0; i < 4; i++)
      b[i] = *(const short8*)&Bs[cur][(wc * 64 + i * 16 + (l & 15)) * 32 + (l >> 4) * 8];
#pragma unroll
    for (int i = 0; i < 4; i++)
#pragma unroll
      for (int j = 0; j < 4; j++)
        acc[i][j] = __builtin_amdgcn_mfma_f32_16x16x32_bf16(a[i], b[j], acc[i][j], 0, 0, 0);
    __syncthreads();
    cur ^= 1;
  }
#undef GSTAGE

#pragma unroll
  for (int i = 0; i < 4; i++) {
#pragma unroll
    for (int j2 = 0; j2 < 4; j2++) {
      int mm = m0 + wr * 64 + i * 16 + (l >> 4) * 4 + j2;
      int bidx = mm >> 11, s = mm & 2047;
#pragma unroll
      for (int nj = 0; nj < 4; nj++) {
        int e = n0 + wc * 64 + nj * 16 + (l & 15);
        float val = acc[i][nj][j2] + bias[e];
        int h = e >> 6, dk = e & 63;
        int bh = bidx * H_ + h;
        if (which == 0)      Qw[(bh * S_ + s) * DK_ + dk] = f2b(val * LOG2E_OVER8);
        else if (which == 1) Kw[(bh * S_ + s) * DK_ + dk] = f2b(val);
        else                 VTw[(bh * DK_ + dk) * S_ + s] = f2b(val);
      }
    }
  }
}

// ---------------- flash attention v10 (verbatim: 43.4 us proven) ----------
#define KVB   32
#define SHALF 1024
__launch_bounds__(256, 3)
__global__ void attn_kernel(const short* __restrict__ Qw, const short* __restrict__ Kw,
                            const short* __restrict__ VTw, short* __restrict__ ctx) {
  __shared__ short Ksh[2][2][KVB * DK_];   // [stream][buf][32 rows][64]
  __shared__ short Vsh[2][2][KVB * DK_];   // [stream][buf] pair-packed rows

  const int t = threadIdx.x, l = t & 63, w = t >> 6;
  const int s = w >> 1, qh = w & 1;
  const int L = blockIdx.y * 32 + blockIdx.x;
  const int xcd = L & 7, idx = L >> 3;
  const int bh = xcd * 3 + (idx >> 5);
  const int qblk = idx & 31;
  const int q0 = qblk * 64 + qh * 32;
  const int bq = bh / H_, h = bh - bq * H_;
  const short* Qh = Qw + bh * S_ * DK_;
  const short* Kh = Kw + (bh * S_ + s * SHALF) * DK_;
  const short* Vh = VTw + bh * DK_ * S_ + s * SHALF;

  const int tt = t & 127;
  const int kr0 = tt >> 3, kc0 = tt & 7;
  const int koff0 = kr0 * DK_ + ((kc0 ^ (kr0 & 7)) << 3);
  const int vc8 = (tt & 7) ^ ((tt >> 3) & 7);
  const int vr0 = 2 * (tt >> 3) + (vc8 >> 2);
  const int voff0 = vr0 * S_ + ((vc8 & 3) << 3);

#define STAGE(buf, kt) do { \
    gl_lds16(Kh + (kt) * DK_ + koff0,        &Ksh[s][buf][tt * 8]); \
    gl_lds16(Kh + (kt) * DK_ + koff0 + 1024, &Ksh[s][buf][tt * 8 + 1024]); \
    gl_lds16(Vh + (kt) + voff0,              &Vsh[s][buf][tt * 8]); \
    gl_lds16(Vh + (kt) + voff0 + 32 * S_,    &Vsh[s][buf][tt * 8 + 1024]); \
  } while (0)

  short8 qf[2][2];
#pragma unroll
  for (int mi = 0; mi < 2; mi++)
#pragma unroll
    for (int ks = 0; ks < 2; ks++)
      qf[mi][ks] = *(const short8*)&Qh[(q0 + 16 * mi + (l & 15)) * DK_ + ks * 32 + (l >> 4) * 8];

  f32x4 acc_o[2][4] = {};
  float l_run[2] = {0.f, 0.f};   // per-lane PARTIAL sums

  STAGE(0, 0);
  __syncthreads();
  int cur = 0;

  for (int kt = 0; kt < SHALF; kt += KVB) {
    if (kt + KVB < SHALF) STAGE(cur ^ 1, kt + KVB);

    f32x4 acc_s[2][2] = {};
    __builtin_amdgcn_s_setprio(1);
#pragma unroll
    for (int ni = 0; ni < 2; ni++) {
      int r = (l & 15) + 16 * ni;
#pragma unroll
      for (int ks = 0; ks < 2; ks++) {
        int cc = (l >> 4) + 4 * ks;
        short8 kf = *(const short8*)&Ksh[s][cur][r * DK_ + ((cc ^ (r & 7)) << 3)];
        acc_s[0][ni] = __builtin_amdgcn_mfma_f32_16x16x32_bf16(kf, qf[0][ks], acc_s[0][ni], 0, 0, 0);
        acc_s[1][ni] = __builtin_amdgcn_mfma_f32_16x16x32_bf16(kf, qf[1][ks], acc_s[1][ni], 0, 0, 0);
      }
    }
    __builtin_amdgcn_s_setprio(0);

#pragma unroll
    for (int mi = 0; mi < 2; mi++) {
      float sum = 0.f;
#pragma unroll
      for (int ni = 0; ni < 2; ni++)
#pragma unroll
        for (int j = 0; j < 4; j++) {
          float p = __builtin_amdgcn_exp2f(acc_s[mi][ni][j]);
          acc_s[mi][ni][j] = p;
          sum += p;
        }
      l_run[mi] += sum;
    }

    union PK { unsigned u[4]; short8 v; } pa0, pa1;
    pa0.u[0] = cvt_pk_bf16(acc_s[0][0][0], acc_s[0][0][1]);
    pa0.u[1] = cvt_pk_bf16(acc_s[0][0][2], acc_s[0][0][3]);
    pa0.u[2] = cvt_pk_bf16(acc_s[0][1][0], acc_s[0][1][1]);
    pa0.u[3] = cvt_pk_bf16(acc_s[0][1][2], acc_s[0][1][3]);
    pa1.u[0] = cvt_pk_bf16(acc_s[1][0][0], acc_s[1][0][1]);
    pa1.u[1] = cvt_pk_bf16(acc_s[1][0][2], acc_s[1][0][3]);
    pa1.u[2] = cvt_pk_bf16(acc_s[1][1][0], acc_s[1][1][1]);
    pa1.u[3] = cvt_pk_bf16(acc_s[1][1][2], acc_s[1][1][3]);

    __builtin_amdgcn_s_setprio(1);
    {
      const int cc = l >> 4;
      union V8 { short4 h[2]; short8 v; };
#pragma unroll
      for (int nd = 0; nd < 4; nd++) {
        int vr = (l & 15) + 16 * nd, rp = vr >> 1;
        int ph0 = (((vr & 1) << 2) | (cc >> 1)) ^ (rp & 7);
        int ph1 = (((vr & 1) << 2) | (2 + (cc >> 1))) ^ (rp & 7);
        V8 vf;
        vf.h[0] = *(const short4*)&Vsh[s][cur][rp * 64 + ph0 * 8 + (cc & 1) * 4];
        vf.h[1] = *(const short4*)&Vsh[s][cur][rp * 64 + ph1 * 8 + (cc & 1) * 4];
        acc_o[0][nd] = __builtin_amdgcn_mfma_f32_16x16x32_bf16(pa0.v, vf.v, acc_o[0][nd], 0, 0, 0);
        acc_o[1][nd] = __builtin_amdgcn_mfma_f32_16x16x32_bf16(pa1.v, vf.v, acc_o[1][nd], 0, 0, 0);
      }
    }
    __builtin_amdgcn_s_setprio(0);

    __syncthreads();
    cur ^= 1;
  }

#pragma unroll
  for (int mi = 0; mi < 2; mi++) {
    l_run[mi] += __shfl_xor(l_run[mi], 16);
    l_run[mi] += __shfl_xor(l_run[mi], 32);
  }

  __syncthreads();
  float* Oshf = (float*)&Ksh[0][0][0];
  float* Lsh  = (float*)&Vsh[0][0][0];
  if (s == 1) {
#pragma unroll
    for (int mi = 0; mi < 2; mi++)
#pragma unroll
      for (int nd = 0; nd < 4; nd++)
#pragma unroll
        for (int j = 0; j < 4; j++)
          Oshf[qh * 2048 + (16 * mi + (l >> 4) * 4 + j) * 64 + (l & 15) + 16 * nd] = acc_o[mi][nd][j];
    if (l < 16) {
      Lsh[(qh * 2 + 0) * 16 + l] = l_run[0];
      Lsh[(qh * 2 + 1) * 16 + l] = l_run[1];
    }
  }
  __syncthreads();
  if (s == 0) {
#pragma unroll
    for (int mi = 0; mi < 2; mi++) {
#pragma unroll
      for (int j = 0; j < 4; j++) {
        int src = ((l >> 4) << 2) + j;
        float llo = __shfl(l_run[mi], src);
        float lhi = Lsh[(qh * 2 + mi) * 16 + src];
        float inv = 1.f / (llo + lhi);
        int srow = q0 + 16 * mi + src;
#pragma unroll
        for (int nd = 0; nd < 4; nd++) {
          float ohi = Oshf[qh * 2048 + (16 * mi + src) * 64 + (l & 15) + 16 * nd];
          float val = (acc_o[mi][nd][j] + ohi) * inv;
          ctx[(bq * S_ + srow) * D_ + h * DK_ + (l & 15) + 16 * nd] = f2b(val);
        }
      }
    }
  }
#undef STAGE
}

// ---------------- output projection (128x128, dbuf) + XCD swizzle ----------------
// 192 = 8 x 24 (bijective): xcd owns ctx rows [xcd*512, xcd*512+512) x all n0.
__launch_bounds__(256)
__global__ void oproj_kernel(const short* __restrict__ ctx, const short* __restrict__ Wo,
                             const float* __restrict__ bo, float* __restrict__ out) {
  __shared__ short As[2][128 * 32];
  __shared__ short Bs[2][128 * 32];
  const int lid = blockIdx.y * 6 + blockIdx.x;
  const int xcd = lid & 7, ii = lid >> 3;        // ii in [0,24)
  const int m0 = (xcd * 4 + ii / 6) * 128;
  const int n0 = (ii % 6) * 128;
  const int t = threadIdx.x, l = t & 63, w = t >> 6;
  const int wr = w >> 1, wc = w & 1;

  f32x4 acc[4][4] = {};
  const int srow = t >> 2, sseg = (t & 3) * 8;

#define GSTAGE(buf, k0) do { \
    gl_lds16(ctx + (m0 + srow) * D_ + (k0) + sseg,      &As[buf][t * 8]); \
    gl_lds16(ctx + (m0 + 64 + srow) * D_ + (k0) + sseg, &As[buf][(t + 256) * 8]); \
    gl_lds16(Wo  + (n0 + srow) * D_ + (k0) + sseg,      &Bs[buf][t * 8]); \
    gl_lds16(Wo  + (n0 + 64 + srow) * D_ + (k0) + sseg, &Bs[buf][(t + 256) * 8]); \
  } while (0)

  GSTAGE(0, 0);
  __syncthreads();
  int cur = 0;
  for (int k0 = 0; k0 < D_; k0 += 32) {
    if (k0 + 32 < D_) GSTAGE(cur ^ 1, k0 + 32);
    short8 a[4], b[4];
#pragma unroll
    for (int i = 0; i < 4; i++)
      a[i] = *(const short8*)&As[cur][(wr * 64 + i * 16 + (l & 15)) * 32 + (l >> 4) * 8];
#pragma unroll
    for (int i = 0; i < 4; i++)
      b[i] = *(const short8*)&Bs[cur][(wc * 64 + i * 16 + (l & 15)) * 32 + (l >> 4) * 8];
#pragma unroll
    for (int i = 0; i < 4; i++)
#pragma unroll
      for (int j = 0; j < 4; j++)
        acc[i][j] = __builtin_amdgcn_mfma_f32_16x16x32_bf16(a[i], b[j], acc[i][j], 0, 0, 0);
    __syncthreads();
    cur ^= 1;
  }
#undef GSTAGE

#pragma unroll
  for (int i = 0; i < 4; i++) {
#pragma unroll
    for (int j2 = 0; j2 < 4; j2++) {
      int mm = m0 + wr * 64 + i * 16 + (l >> 4) * 4 + j2;
#pragma unroll
      for (int nj = 0; nj < 4; nj++) {
        int e = n0 + wc * 64 + nj * 16 + (l & 15);
        out[mm * D_ + e] = acc[i][nj][j2] + bo[e];
      }
    }
  }
}

extern "C" void kernel_launch(void* const* d_in, const int* in_sizes, int n_in,
                              void* d_out, int out_size, void* d_ws, size_t ws_size,
                              hipStream_t stream) {
  (void)in_sizes; (void)n_in; (void)out_size; (void)ws_size;
  const float* x  = (const float*)d_in[0];
  const float* wq = (const float*)d_in[1];
  const float* bq = (const float*)d_in[2];
  const float* wk = (const float*)d_in[3];
  const float* bk = (const float*)d_in[4];
  const float* wv = (const float*)d_in[5];
  const float* bv = (const float*)d_in[6];
  const float* wo = (const float*)d_in[7];
  const float* bo = (const float*)d_in[8];
  float* out = (float*)d_out;

  short* xb  = (short*)d_ws;            // R*D bf16
  short* wb  = xb + R_ * D_;            // 4*D*D bf16 (q,k,v,o)
  short* Qw  = wb + 4 * D_ * D_;        // [B,H,S,DK]
  short* Kw  = Qw + R_ * D_;            // [B,H,S,DK]
  short* VTw = Kw + R_ * D_;            // [B,H,DK,S]
  short* ctx = VTw + R_ * D_;           // [B,S,D]

  cvt_kernel<<<5376, 256, 0, stream>>>(x, wq, wk, wv, wo, xb, wb);
  qkv_gemm_kernel<<<dim3(6, 32, 3), 256, 0, stream>>>(xb, wb, bq, bk, bv, Qw, Kw, VTw);
  attn_kernel<<<dim3(32, 24), 256, 0, stream>>>(Qw, Kw, VTw, ctx);
  oproj_kernel<<<dim3(6, 32), 256, 0, stream>>>(ctx, wb + 3 * D_ * D_, bo, out);
}

// Round 17
// 97.696 us; speedup vs baseline: 1.2937x; 1.0295x over previous
//
#include <hip/hip_runtime.h>
#include <hip/hip_bf16.h>

#define B_   2
#define S_   2048
#define D_   768
#define H_   12
#define DK_  64
#define R_   (B_*S_)   // 4096 rows total
#define LOG2E_OVER8 0.18033688011112042f

typedef __attribute__((ext_vector_type(8))) short short8;
typedef __attribute__((ext_vector_type(4))) float f32x4;

__device__ __forceinline__ short f2b(float f) {
  union { float f; unsigned u; } x; x.f = f;
  unsigned r = x.u + 0x7fffu + ((x.u >> 16) & 1u);
  return (short)(r >> 16);
}

__device__ __forceinline__ unsigned cvt_pk_bf16(float lo, float hi) {
  unsigned r;
  asm("v_cvt_pk_bf16_f32 %0, %1, %2" : "=v"(r) : "v"(lo), "v"(hi));
  return r;
}

__device__ __forceinline__ void gl_lds16(const short* g, short* l) {
  __builtin_amdgcn_global_load_lds(
      (const __attribute__((address_space(1))) void*)g,
      (__attribute__((address_space(3))) void*)l, 16, 0, 0);
}

// ---------------- fp32 -> bf16 conversion (x + 4 weights) ----------------
__global__ void cvt_kernel(const float* __restrict__ x,
                           const float* __restrict__ wq, const float* __restrict__ wk,
                           const float* __restrict__ wv, const float* __restrict__ wo,
                           short* __restrict__ xb, short* __restrict__ wb) {
  const int XQ = R_ * D_ / 4;
  const int WQ = D_ * D_ / 4;
  int idx = blockIdx.x * blockDim.x + threadIdx.x;
  const float* src; short* dst; int off;
  if (idx < XQ) { src = x; dst = xb; off = idx; }
  else {
    int wi = idx - XQ; int w = wi / WQ; off = wi - w * WQ;
    if      (w == 0) { src = wq; dst = wb; }
    else if (w == 1) { src = wk; dst = wb + D_*D_; }
    else if (w == 2) { src = wv; dst = wb + 2*D_*D_; }
    else             { src = wo; dst = wb + 3*D_*D_; }
  }
  float4 v = ((const float4*)src)[off];
  short4 o;
  o.x = f2b(v.x); o.y = f2b(v.y); o.z = f2b(v.z); o.w = f2b(v.w);
  ((short4*)dst)[off] = o;
}

// ---------------- QKV projection (128x128, BK=32, dbuf — round-10 proven) ----------
__launch_bounds__(256)
__global__ void qkv_gemm_kernel(const short* __restrict__ xb, const short* __restrict__ wb,
                                const float* __restrict__ bq, const float* __restrict__ bk,
                                const float* __restrict__ bv,
                                short* __restrict__ Qw, short* __restrict__ Kw,
                                short* __restrict__ VTw) {
  __shared__ short As[2][128 * 32];
  __shared__ short Bs[2][128 * 32];
  const int which = blockIdx.z;
  const short* W = wb + which * (D_ * D_);
  const float* bias = (which == 0) ? bq : (which == 1) ? bk : bv;
  const int n0 = blockIdx.x * 128, m0 = blockIdx.y * 128;
  const int t = threadIdx.x, l = t & 63, w = t >> 6;
  const int wr = w >> 1, wc = w & 1;

  f32x4 acc[4][4] = {};
  const int srow = t >> 2, sseg = (t & 3) * 8;

#define GSTAGE(buf, k0) do { \
    gl_lds16(xb + (m0 + srow) * D_ + (k0) + sseg,      &As[buf][t * 8]); \
    gl_lds16(xb + (m0 + 64 + srow) * D_ + (k0) + sseg, &As[buf][(t + 256) * 8]); \
    gl_lds16(W  + (n0 + srow) * D_ + (k0) + sseg,      &Bs[buf][t * 8]); \
    gl_lds16(W  + (n0 + 64 + srow) * D_ + (k0) + sseg, &Bs[buf][(t + 256) * 8]); \
  } while (0)

  GSTAGE(0, 0);
  __syncthreads();
  int cur = 0;
  for (int k0 = 0; k0 < D_; k0 += 32) {
    if (k0 + 32 < D_) GSTAGE(cur ^ 1, k0 + 32);
    short8 a[4], b[4];
#pragma unroll
    for (int i = 0; i < 4; i++)
      a[i] = *(const short8*)&As[cur][(wr * 64 + i * 16 + (l & 15)) * 32 + (l >> 4) * 8];
#pragma unroll
    for (int i = 0; i < 4; i++)
      b[i] = *(const short8*)&Bs[cur][(wc * 64 + i * 16 + (l & 15)) * 32 + (l >> 4) * 8];
#pragma unroll
    for (int i = 0; i < 4; i++)
#pragma unroll
      for (int j = 0; j < 4; j++)
        acc[i][j] = __builtin_amdgcn_mfma_f32_16x16x32_bf16(a[i], b[j], acc[i][j], 0, 0, 0);
    __syncthreads();
    cur ^= 1;
  }
#undef GSTAGE

#pragma unroll
  for (int i = 0; i < 4; i++) {
#pragma unroll
    for (int j2 = 0; j2 < 4; j2++) {
      int mm = m0 + wr * 64 + i * 16 + (l >> 4) * 4 + j2;
      int bidx = mm >> 11, s = mm & 2047;
#pragma unroll
      for (int nj = 0; nj < 4; nj++) {
        int e = n0 + wc * 64 + nj * 16 + (l & 15);
        float val = acc[i][nj][j2] + bias[e];
        int h = e >> 6, dk = e & 63;
        int bh = bidx * H_ + h;
        if (which == 0)      Qw[(bh * S_ + s) * DK_ + dk] = f2b(val * LOG2E_OVER8);
        else if (which == 1) Kw[(bh * S_ + s) * DK_ + dk] = f2b(val);
        else                 VTw[(bh * DK_ + dk) * S_ + s] = f2b(val);
      }
    }
  }
}

// ---------------- flash attention v10 (verbatim: 43.4 us proven) ----------
#define KVB   32
#define SHALF 1024
__launch_bounds__(256, 3)
__global__ void attn_kernel(const short* __restrict__ Qw, const short* __restrict__ Kw,
                            const short* __restrict__ VTw, short* __restrict__ ctx) {
  __shared__ short Ksh[2][2][KVB * DK_];   // [stream][buf][32 rows][64]
  __shared__ short Vsh[2][2][KVB * DK_];   // [stream][buf] pair-packed rows

  const int t = threadIdx.x, l = t & 63, w = t >> 6;
  const int s = w >> 1, qh = w & 1;
  const int L = blockIdx.y * 32 + blockIdx.x;
  const int xcd = L & 7, idx = L >> 3;
  const int bh = xcd * 3 + (idx >> 5);
  const int qblk = idx & 31;
  const int q0 = qblk * 64 + qh * 32;
  const int bq = bh / H_, h = bh - bq * H_;
  const short* Qh = Qw + bh * S_ * DK_;
  const short* Kh = Kw + (bh * S_ + s * SHALF) * DK_;
  const short* Vh = VTw + bh * DK_ * S_ + s * SHALF;

  const int tt = t & 127;
  const int kr0 = tt >> 3, kc0 = tt & 7;
  const int koff0 = kr0 * DK_ + ((kc0 ^ (kr0 & 7)) << 3);
  const int vc8 = (tt & 7) ^ ((tt >> 3) & 7);
  const int vr0 = 2 * (tt >> 3) + (vc8 >> 2);
  const int voff0 = vr0 * S_ + ((vc8 & 3) << 3);

#define STAGE(buf, kt) do { \
    gl_lds16(Kh + (kt) * DK_ + koff0,        &Ksh[s][buf][tt * 8]); \
    gl_lds16(Kh + (kt) * DK_ + koff0 + 1024, &Ksh[s][buf][tt * 8 + 1024]); \
    gl_lds16(Vh + (kt) + voff0,              &Vsh[s][buf][tt * 8]); \
    gl_lds16(Vh + (kt) + voff0 + 32 * S_,    &Vsh[s][buf][tt * 8 + 1024]); \
  } while (0)

  short8 qf[2][2];
#pragma unroll
  for (int mi = 0; mi < 2; mi++)
#pragma unroll
    for (int ks = 0; ks < 2; ks++)
      qf[mi][ks] = *(const short8*)&Qh[(q0 + 16 * mi + (l & 15)) * DK_ + ks * 32 + (l >> 4) * 8];

  f32x4 acc_o[2][4] = {};
  float l_run[2] = {0.f, 0.f};   // per-lane PARTIAL sums

  STAGE(0, 0);
  __syncthreads();
  int cur = 0;

  for (int kt = 0; kt < SHALF; kt += KVB) {
    if (kt + KVB < SHALF) STAGE(cur ^ 1, kt + KVB);

    f32x4 acc_s[2][2] = {};
    __builtin_amdgcn_s_setprio(1);
#pragma unroll
    for (int ni = 0; ni < 2; ni++) {
      int r = (l & 15) + 16 * ni;
#pragma unroll
      for (int ks = 0; ks < 2; ks++) {
        int cc = (l >> 4) + 4 * ks;
        short8 kf = *(const short8*)&Ksh[s][cur][r * DK_ + ((cc ^ (r & 7)) << 3)];
        acc_s[0][ni] = __builtin_amdgcn_mfma_f32_16x16x32_bf16(kf, qf[0][ks], acc_s[0][ni], 0, 0, 0);
        acc_s[1][ni] = __builtin_amdgcn_mfma_f32_16x16x32_bf16(kf, qf[1][ks], acc_s[1][ni], 0, 0, 0);
      }
    }
    __builtin_amdgcn_s_setprio(0);

#pragma unroll
    for (int mi = 0; mi < 2; mi++) {
      float sum = 0.f;
#pragma unroll
      for (int ni = 0; ni < 2; ni++)
#pragma unroll
        for (int j = 0; j < 4; j++) {
          float p = __builtin_amdgcn_exp2f(acc_s[mi][ni][j]);
          acc_s[mi][ni][j] = p;
          sum += p;
        }
      l_run[mi] += sum;
    }

    union PK { unsigned u[4]; short8 v; } pa0, pa1;
    pa0.u[0] = cvt_pk_bf16(acc_s[0][0][0], acc_s[0][0][1]);
    pa0.u[1] = cvt_pk_bf16(acc_s[0][0][2], acc_s[0][0][3]);
    pa0.u[2] = cvt_pk_bf16(acc_s[0][1][0], acc_s[0][1][1]);
    pa0.u[3] = cvt_pk_bf16(acc_s[0][1][2], acc_s[0][1][3]);
    pa1.u[0] = cvt_pk_bf16(acc_s[1][0][0], acc_s[1][0][1]);
    pa1.u[1] = cvt_pk_bf16(acc_s[1][0][2], acc_s[1][0][3]);
    pa1.u[2] = cvt_pk_bf16(acc_s[1][1][0], acc_s[1][1][1]);
    pa1.u[3] = cvt_pk_bf16(acc_s[1][1][2], acc_s[1][1][3]);

    __builtin_amdgcn_s_setprio(1);
    {
      const int cc = l >> 4;
      union V8 { short4 h[2]; short8 v; };
#pragma unroll
      for (int nd = 0; nd < 4; nd++) {
        int vr = (l & 15) + 16 * nd, rp = vr >> 1;
        int ph0 = (((vr & 1) << 2) | (cc >> 1)) ^ (rp & 7);
        int ph1 = (((vr & 1) << 2) | (2 + (cc >> 1))) ^ (rp & 7);
        V8 vf;
        vf.h[0] = *(const short4*)&Vsh[s][cur][rp * 64 + ph0 * 8 + (cc & 1) * 4];
        vf.h[1] = *(const short4*)&Vsh[s][cur][rp * 64 + ph1 * 8 + (cc & 1) * 4];
        acc_o[0][nd] = __builtin_amdgcn_mfma_f32_16x16x32_bf16(pa0.v, vf.v, acc_o[0][nd], 0, 0, 0);
        acc_o[1][nd] = __builtin_amdgcn_mfma_f32_16x16x32_bf16(pa1.v, vf.v, acc_o[1][nd], 0, 0, 0);
      }
    }
    __builtin_amdgcn_s_setprio(0);

    __syncthreads();
    cur ^= 1;
  }

#pragma unroll
  for (int mi = 0; mi < 2; mi++) {
    l_run[mi] += __shfl_xor(l_run[mi], 16);
    l_run[mi] += __shfl_xor(l_run[mi], 32);
  }

  __syncthreads();
  float* Oshf = (float*)&Ksh[0][0][0];
  float* Lsh  = (float*)&Vsh[0][0][0];
  if (s == 1) {
#pragma unroll
    for (int mi = 0; mi < 2; mi++)
#pragma unroll
      for (int nd = 0; nd < 4; nd++)
#pragma unroll
        for (int j = 0; j < 4; j++)
          Oshf[qh * 2048 + (16 * mi + (l >> 4) * 4 + j) * 64 + (l & 15) + 16 * nd] = acc_o[mi][nd][j];
    if (l < 16) {
      Lsh[(qh * 2 + 0) * 16 + l] = l_run[0];
      Lsh[(qh * 2 + 1) * 16 + l] = l_run[1];
    }
  }
  __syncthreads();
  if (s == 0) {
#pragma unroll
    for (int mi = 0; mi < 2; mi++) {
#pragma unroll
      for (int j = 0; j < 4; j++) {
        int src = ((l >> 4) << 2) + j;
        float llo = __shfl(l_run[mi], src);
        float lhi = Lsh[(qh * 2 + mi) * 16 + src];
        float inv = 1.f / (llo + lhi);
        int srow = q0 + 16 * mi + src;
#pragma unroll
        for (int nd = 0; nd < 4; nd++) {
          float ohi = Oshf[qh * 2048 + (16 * mi + src) * 64 + (l & 15) + 16 * nd];
          float val = (acc_o[mi][nd][j] + ohi) * inv;
          ctx[(bq * S_ + srow) * D_ + h * DK_ + (l & 15) + 16 * nd] = f2b(val);
        }
      }
    }
  }
#undef STAGE
}

// ---------------- output projection: 64x128 tile (2x blocks), BK=32, dbuf ----------
__launch_bounds__(256)
__global__ void oproj_kernel(const short* __restrict__ ctx, const short* __restrict__ Wo,
                             const float* __restrict__ bo, float* __restrict__ out) {
  __shared__ short As[2][64 * 32];
  __shared__ short Bs[2][128 * 32];
  const int n0 = blockIdx.x * 128, m0 = blockIdx.y * 64;
  const int t = threadIdx.x, l = t & 63, w = t >> 6;

  f32x4 acc[4][2] = {};
  const int srow = t >> 2, sseg = (t & 3) * 8;

#define GSTAGE(buf, k0) do { \
    gl_lds16(ctx + (m0 + srow) * D_ + (k0) + sseg,      &As[buf][t * 8]); \
    gl_lds16(Wo  + (n0 + srow) * D_ + (k0) + sseg,      &Bs[buf][t * 8]); \
    gl_lds16(Wo  + (n0 + 64 + srow) * D_ + (k0) + sseg, &Bs[buf][(t + 256) * 8]); \
  } while (0)

  GSTAGE(0, 0);
  __syncthreads();
  int cur = 0;
  for (int k0 = 0; k0 < D_; k0 += 32) {
    if (k0 + 32 < D_) GSTAGE(cur ^ 1, k0 + 32);
    short8 a[4], b[2];
#pragma unroll
    for (int i = 0; i < 4; i++)
      a[i] = *(const short8*)&As[cur][(i * 16 + (l & 15)) * 32 + (l >> 4) * 8];
#pragma unroll
    for (int nj = 0; nj < 2; nj++)
      b[nj] = *(const short8*)&Bs[cur][(w * 32 + nj * 16 + (l & 15)) * 32 + (l >> 4) * 8];
#pragma unroll
    for (int i = 0; i < 4; i++)
#pragma unroll
      for (int nj = 0; nj < 2; nj++)
        acc[i][nj] = __builtin_amdgcn_mfma_f32_16x16x32_bf16(a[i], b[nj], acc[i][nj], 0, 0, 0);
    __syncthreads();
    cur ^= 1;
  }
#undef GSTAGE

#pragma unroll
  for (int i = 0; i < 4; i++) {
#pragma unroll
    for (int j2 = 0; j2 < 4; j2++) {
      int mm = m0 + i * 16 + (l >> 4) * 4 + j2;
#pragma unroll
      for (int nj = 0; nj < 2; nj++) {
        int e = n0 + w * 32 + nj * 16 + (l & 15);
        out[mm * D_ + e] = acc[i][nj][j2] + bo[e];
      }
    }
  }
}

extern "C" void kernel_launch(void* const* d_in, const int* in_sizes, int n_in,
                              void* d_out, int out_size, void* d_ws, size_t ws_size,
                              hipStream_t stream) {
  (void)in_sizes; (void)n_in; (void)out_size; (void)ws_size;
  const float* x  = (const float*)d_in[0];
  const float* wq = (const float*)d_in[1];
  const float* bq = (const float*)d_in[2];
  const float* wk = (const float*)d_in[3];
  const float* bk = (const float*)d_in[4];
  const float* wv = (const float*)d_in[5];
  const float* bv = (const float*)d_in[6];
  const float* wo = (const float*)d_in[7];
  const float* bo = (const float*)d_in[8];
  float* out = (float*)d_out;

  short* xb  = (short*)d_ws;            // R*D bf16
  short* wb  = xb + R_ * D_;            // 4*D*D bf16 (q,k,v,o)
  short* Qw  = wb + 4 * D_ * D_;        // [B,H,S,DK]
  short* Kw  = Qw + R_ * D_;            // [B,H,S,DK]
  short* VTw = Kw + R_ * D_;            // [B,H,DK,S]
  short* ctx = VTw + R_ * D_;           // [B,S,D]

  cvt_kernel<<<5376, 256, 0, stream>>>(x, wq, wk, wv, wo, xb, wb);
  qkv_gemm_kernel<<<dim3(6, 32, 3), 256, 0, stream>>>(xb, wb, bq, bk, bv, Qw, Kw, VTw);
  attn_kernel<<<dim3(32, 24), 256, 0, stream>>>(Qw, Kw, VTw, ctx);
  oproj_kernel<<<dim3(6, 64), 256, 0, stream>>>(ctx, wb + 3 * D_ * D_, bo, out);
}